// Round 4
// baseline (527.236 us; speedup 1.0000x reference)
//
#include <hip/hip_runtime.h>

// ---------------- problem constants ----------------
#define CCH   256
#define HH    96
#define WW    96
#define HO    94
#define LL    8836        // 94*94 patches
#define DD    2304        // 256*9
#define LPAD  8960        // 35 * 256

// GEMM geometry: 256x256 tile, 8 waves (2M x 4N), 512 threads.
// K processed in 72 kk-slices of 32; LDS = ring of 4 A-slices + 4 B-slices
// (16 KB each = 256 rows x 32 bf16), total 128 KiB.
#define BM2   256
#define NT2   35          // 8960/256
#define NPH   72          // 2304/32 phases
#define ASL   8192        // elements per slice (256*32)
#define BBASE 32768       // B slices start (elements)

typedef unsigned short ushort_t;
typedef unsigned long long u64;

using short8 = __attribute__((ext_vector_type(8))) short;
using f32x4  = __attribute__((ext_vector_type(4))) float;

// ---------------- workspace layout (bytes) ----------------
#define OFF_B     41287680ull
#define OFF_RNB   82575360ull
#define OFF_N2B   82611200ull
#define OFF_W2X   82647040ull
#define OFF_P2    82682880ull
#define OFF_BEST  82756608ull

__device__ __forceinline__ ushort_t f2bf(float f) {
    unsigned u = __float_as_uint(f);
    unsigned r = (u + 0x7FFFu + ((u >> 16) & 1u)) >> 16;  // RNE
    return (ushort_t)r;
}

__device__ __forceinline__ void gload16(const ushort_t* g, ushort_t* l) {
    __builtin_amdgcn_global_load_lds(
        (const __attribute__((address_space(1))) unsigned int*)g,
        (__attribute__((address_space(3))) unsigned int*)l,
        16, 0, 0);
}

// ---- 1: per-pixel channel sum of squares for both images ----
__global__ __launch_bounds__(256) void k_chan_sumsq(const float* __restrict__ st,
                                                    const float* __restrict__ x,
                                                    float* __restrict__ P2) {
    int p = blockIdx.x * 256 + threadIdx.x;
    if (p >= 2 * HH * WW) return;
    const float* img = (p < HH * WW) ? st : x;
    int pp = (p < HH * WW) ? p : p - HH * WW;
    float s = 0.f;
#pragma unroll 4
    for (int c = 0; c < CCH; ++c) {
        float v = img[c * (HH * WW) + pp];
        s += v * v;
    }
    P2[p] = s;
}

// ---- 2: 3x3 window sums -> style inv-norms, style norm^2, x patch norm^2 ----
__global__ __launch_bounds__(256) void k_win(const float* __restrict__ P2,
                                             float* __restrict__ rnB,
                                             float* __restrict__ n2B,
                                             float* __restrict__ win2x) {
    int i = blockIdx.x * 256 + threadIdx.x;
    if (i >= LL) return;
    int y = i / HO, xc = i % HO;
    float ss = 0.f, sx = 0.f;
#pragma unroll
    for (int kh = 0; kh < 3; ++kh)
#pragma unroll
        for (int kw = 0; kw < 3; ++kw) {
            int off = (y + kh) * WW + xc + kw;
            ss += P2[off];
            sx += P2[HH * WW + off];
        }
    rnB[i] = 1.f / (sqrtf(ss) + 1e-8f);
    n2B[i] = ss;
    win2x[i] = sx;
}

// ---- 3: pack patches to bf16 [LPAD][DD]; A = raw x, B = normalized style ----
__global__ __launch_bounds__(256) void k_pack(const float* __restrict__ x,
                                              const float* __restrict__ st,
                                              const float* __restrict__ rnB,
                                              ushort_t* __restrict__ A,
                                              ushort_t* __restrict__ Bm) {
    int row = blockIdx.x;
    bool isB = row >= LPAD;
    int i = isB ? row - LPAD : row;
    ushort_t* dst = (isB ? Bm : A) + (size_t)i * DD + threadIdx.x * 9;
    if (i >= LL) {
#pragma unroll
        for (int k = 0; k < 9; ++k) dst[k] = 0;
        return;
    }
    int y = i / HO, xc = i % HO;
    const float* src = isB ? st : x;
    float scale = isB ? rnB[i] : 1.f;
    const float* base = src + (size_t)threadIdx.x * (HH * WW) + y * WW + xc;
#pragma unroll
    for (int kh = 0; kh < 3; ++kh)
#pragma unroll
        for (int kw = 0; kw < 3; ++kw)
            dst[kh * 3 + kw] = f2bf(base[kh * WW + kw] * scale);
}

// ---- 4: fused GEMM (A * B^T) + per-row argmax, kk-slice ring schedule ----
__global__ __launch_bounds__(512, 2) void k_gemm2(const ushort_t* __restrict__ A,
                                                  const ushort_t* __restrict__ Bm,
                                                  u64* __restrict__ best) {
    extern __shared__ __align__(16) ushort_t lds[];  // 128 KiB

    const int t = threadIdx.x;
    const int wid = t >> 6, lane = t & 63;
    const int wr = wid >> 2, wc = wid & 3;
    const int l15 = lane & 15, l4 = lane >> 4;

    // T1: bijective XCD swizzle (m204), nwg = 1225
    const int nwg = NT2 * NT2;
    const int q = nwg >> 3, r = nwg & 7;  // 153, 1
    const int bid = blockIdx.x;
    const int xcd = bid & 7, loc = bid >> 3;
    const int swz = ((xcd < r) ? xcd * (q + 1) : r * (q + 1) + (xcd - r) * q) + loc;
    const int it = swz / NT2, jt = swz % NT2;

    // staging source: thread t covers chunk c=t (rows 0..127 of panel) and
    // c=t+512 (rows 128..255); logical k-group pre-swizzled: (c&3)^((c>>3)&3)
    const int gsrc = (t & 3) ^ ((t >> 3) & 3);
    const ushort_t* pA0 = A  + (size_t)(it * BM2 + (t >> 2)) * DD + gsrc * 8;
    const ushort_t* pB0 = Bm + (size_t)(jt * BM2 + (t >> 2)) * DD + gsrc * 8;

    // fragment read offsets (swizzled): phys group = l4 ^ ((row>>1)&3)
    const int sp8 = (l4 ^ ((l15 >> 1) & 3)) * 8;
    int aoff[8], boff[4];
#pragma unroll
    for (int mi = 0; mi < 8; ++mi)
        aoff[mi] = (wr * 128 + mi * 16 + l15) * 32 + sp8;
#pragma unroll
    for (int ni = 0; ni < 4; ++ni)
        boff[ni] = (wc * 64 + ni * 16 + l15) * 32 + sp8;

    f32x4 acc[8][4];
#pragma unroll
    for (int mi = 0; mi < 8; ++mi)
#pragma unroll
        for (int ni = 0; ni < 4; ++ni)
            acc[mi][ni] = (f32x4){0.f, 0.f, 0.f, 0.f};

    // prologue: stage slices 0,1,2 (A then B per slice, slice-ordered queue)
#define PSTAGE(S)                                                            \
    do {                                                                     \
        const ushort_t* sa = pA0 + (size_t)(S) * 32;                         \
        const ushort_t* sb = pB0 + (size_t)(S) * 32;                         \
        gload16(sa,          lds + (S) * ASL + t * 8);                       \
        gload16(sa + 294912, lds + (S) * ASL + 4096 + t * 8);                \
        gload16(sb,          lds + BBASE + (S) * ASL + t * 8);               \
        gload16(sb + 294912, lds + BBASE + (S) * ASL + 4096 + t * 8);        \
    } while (0)
    PSTAGE(0); PSTAGE(1); PSTAGE(2);
#undef PSTAGE
    asm volatile("s_waitcnt vmcnt(8)" ::: "memory");  // slice 0 landed
    __builtin_amdgcn_sched_barrier(0);
    __builtin_amdgcn_s_barrier();

// One phase: consume slice kb+U (slot U), stage slice kb+U+3 (slot (U+3)&3).
#define PHASE(U)                                                             \
    {                                                                        \
        short8 af[8], bfr[4];                                                \
        _Pragma("unroll")                                                    \
        for (int mi = 0; mi < 8; ++mi)                                       \
            af[mi] = *(const short8*)(lds + (U) * ASL + aoff[mi]);           \
        _Pragma("unroll")                                                    \
        for (int ni = 0; ni < 4; ++ni)                                       \
            bfr[ni] = *(const short8*)(lds + BBASE + (U) * ASL + boff[ni]);  \
        {                                                                    \
            const ushort_t* sa = pA0 + (size_t)(kb + (U) + 3) * 32;          \
            const ushort_t* sb = pB0 + (size_t)(kb + (U) + 3) * 32;          \
            ushort_t* da = lds + (((U) + 3) & 3) * ASL + t * 8;              \
            gload16(sa,          da);                                        \
            gload16(sa + 294912, da + 4096);                                 \
            gload16(sb,          da + BBASE);                                \
            gload16(sb + 294912, da + BBASE + 4096);                         \
        }                                                                    \
        asm volatile("s_waitcnt vmcnt(8)" ::: "memory");                     \
        __builtin_amdgcn_sched_barrier(0);                                   \
        __builtin_amdgcn_s_barrier();                                        \
        asm volatile("s_waitcnt lgkmcnt(0)" ::: "memory");                   \
        __builtin_amdgcn_sched_barrier(0);                                   \
        __builtin_amdgcn_s_setprio(1);                                       \
        _Pragma("unroll")                                                    \
        for (int mi = 0; mi < 8; ++mi)                                       \
            _Pragma("unroll")                                                \
            for (int ni = 0; ni < 4; ++ni)                                   \
                acc[mi][ni] = __builtin_amdgcn_mfma_f32_16x16x32_bf16(       \
                    af[mi], bfr[ni], acc[mi][ni], 0, 0, 0);                  \
        __builtin_amdgcn_s_setprio(0);                                       \
        __builtin_amdgcn_s_barrier();                                        \
    }

    for (int kt = 0; kt < NPH / 4; ++kt) {
        const int kb = kt * 4;
        PHASE(0)
        PHASE(1)
        PHASE(2)
        PHASE(3)
    }
#undef PHASE

    // epilogue: per output row, max over this block's 256 j's, merge globally
    const int jbase = jt * BM2 + wc * 64 + l15;
#pragma unroll
    for (int mi = 0; mi < 8; ++mi) {
#pragma unroll
        for (int rr = 0; rr < 4; ++rr) {
            float bv = -3.4e38f;
            int bj = 0x7FFFFFFF;
#pragma unroll
            for (int ni = 0; ni < 4; ++ni) {
                int j = jbase + ni * 16;
                float v = acc[mi][ni][rr];
                if (j < LL && (v > bv || (v == bv && j < bj))) { bv = v; bj = j; }
            }
#pragma unroll
            for (int m = 1; m < 16; m <<= 1) {
                float ov = __shfl_xor(bv, m, 64);
                int oj = __shfl_xor(bj, m, 64);
                if (ov > bv || (ov == bv && oj < bj)) { bv = ov; bj = oj; }
            }
            if (l15 == 0) {
                int i = it * BM2 + wr * 128 + mi * 16 + l4 * 4 + rr;
                if (i < LL) {
                    unsigned u = __float_as_uint(bv);
                    unsigned s = (bv < 0.f) ? ~u : (u | 0x80000000u);
                    u64 packed = ((u64)s << 32) | (unsigned)(~(unsigned)bj);
                    atomicMax(&best[i], packed);
                }
            }
        }
    }
}

// ---- 5: final scalar ----
__global__ __launch_bounds__(256) void k_final(const u64* __restrict__ best,
                                               const float* __restrict__ rnB,
                                               const float* __restrict__ n2B,
                                               const float* __restrict__ win2x,
                                               float* __restrict__ out) {
    int i = blockIdx.x * 256 + threadIdx.x;
    float contrib = 0.f;
    if (i < LL) {
        u64 p = best[i];
        unsigned s = (unsigned)(p >> 32);
        unsigned ub = (s & 0x80000000u) ? (s & 0x7FFFFFFFu) : ~s;
        float bv = __uint_as_float(ub);
        int j = (int)(~(unsigned)(p & 0xFFFFFFFFull));
        float dot = bv / rnB[j];
        contrib = win2x[i] + n2B[j] - 2.f * dot;
    }
    float sred = contrib;
#pragma unroll
    for (int o = 32; o > 0; o >>= 1) sred += __shfl_down(sred, o, 64);
    __shared__ float red[4];
    if ((threadIdx.x & 63) == 0) red[threadIdx.x >> 6] = sred;
    __syncthreads();
    if (threadIdx.x == 0) {
        float tot = red[0] + red[1] + red[2] + red[3];
        atomicAdd(out, tot * (1.0f / ((float)DD * (float)LL)));
    }
}

extern "C" void kernel_launch(void* const* d_in, const int* in_sizes, int n_in,
                              void* d_out, int out_size, void* d_ws, size_t ws_size,
                              hipStream_t stream) {
    const float* x  = (const float*)d_in[0];
    const float* st = (const float*)d_in[1];
    char* ws = (char*)d_ws;

    ushort_t* A    = (ushort_t*)ws;
    ushort_t* Bm   = (ushort_t*)(ws + OFF_B);
    float* rnB     = (float*)(ws + OFF_RNB);
    float* n2B     = (float*)(ws + OFF_N2B);
    float* win2x   = (float*)(ws + OFF_W2X);
    float* P2      = (float*)(ws + OFF_P2);
    u64* best      = (u64*)(ws + OFF_BEST);
    float* out     = (float*)d_out;

    hipFuncSetAttribute((const void*)k_gemm2,
                        hipFuncAttributeMaxDynamicSharedMemorySize, 131072);

    hipMemsetAsync(best, 0, (size_t)LL * 8, stream);
    hipMemsetAsync(out, 0, sizeof(float), stream);

    k_chan_sumsq<<<dim3(72), dim3(256), 0, stream>>>(st, x, P2);
    k_win<<<dim3(35), dim3(256), 0, stream>>>(P2, rnB, n2B, win2x);
    k_pack<<<dim3(2 * LPAD), dim3(256), 0, stream>>>(x, st, rnB, A, Bm);
    k_gemm2<<<dim3(NT2 * NT2), dim3(512), 131072, stream>>>(A, Bm, best);
    k_final<<<dim3(35), dim3(256), 0, stream>>>(best, rnB, n2B, win2x, out);
}

// Round 5
// 511.604 us; speedup vs baseline: 1.0306x; 1.0306x over previous
//
#include <hip/hip_runtime.h>

// ---------------- problem constants ----------------
#define CCH   256
#define HH    96
#define WW    96
#define HO    94
#define LL    8836        // 94*94 patches
#define DD    2304        // 256*9
#define LPAD  8960        // 35 * 256

// GEMM geometry: 256x256 tile, 8 waves (2M x 4N), 512 threads.
// K processed in 72 kk-slices of 32; LDS = ring of 4 A-slices + 4 B-slices
// (16 KB each = 256 rows x 32 bf16), total 128 KiB.
#define BM2   256
#define NT2   35          // 8960/256
#define NPH   72          // 2304/32 phases
#define ASL   8192        // elements per slice (256*32)
#define BBASE 32768       // B slices start (elements)

typedef unsigned short ushort_t;
typedef unsigned long long u64;

using short8 = __attribute__((ext_vector_type(8))) short;
using f32x4  = __attribute__((ext_vector_type(4))) float;

// ---------------- workspace layout (bytes) ----------------
#define OFF_B     41287680ull
#define OFF_RNB   82575360ull
#define OFF_N2B   82611200ull
#define OFF_W2X   82647040ull
#define OFF_P2    82682880ull
#define OFF_BEST  82756608ull

__device__ __forceinline__ ushort_t f2bf(float f) {
    unsigned u = __float_as_uint(f);
    unsigned r = (u + 0x7FFFu + ((u >> 16) & 1u)) >> 16;  // RNE
    return (ushort_t)r;
}

__device__ __forceinline__ void gload16(const ushort_t* g, ushort_t* l) {
    __builtin_amdgcn_global_load_lds(
        (const __attribute__((address_space(1))) unsigned int*)g,
        (__attribute__((address_space(3))) unsigned int*)l,
        16, 0, 0);
}

// ---- 1: per-pixel channel sum of squares for both images ----
__global__ __launch_bounds__(256) void k_chan_sumsq(const float* __restrict__ st,
                                                    const float* __restrict__ x,
                                                    float* __restrict__ P2) {
    int p = blockIdx.x * 256 + threadIdx.x;
    if (p >= 2 * HH * WW) return;
    const float* img = (p < HH * WW) ? st : x;
    int pp = (p < HH * WW) ? p : p - HH * WW;
    float s = 0.f;
#pragma unroll 4
    for (int c = 0; c < CCH; ++c) {
        float v = img[c * (HH * WW) + pp];
        s += v * v;
    }
    P2[p] = s;
}

// ---- 2: 3x3 window sums -> style inv-norms, style norm^2, x patch norm^2 ----
__global__ __launch_bounds__(256) void k_win(const float* __restrict__ P2,
                                             float* __restrict__ rnB,
                                             float* __restrict__ n2B,
                                             float* __restrict__ win2x) {
    int i = blockIdx.x * 256 + threadIdx.x;
    if (i >= LL) return;
    int y = i / HO, xc = i % HO;
    float ss = 0.f, sx = 0.f;
#pragma unroll
    for (int kh = 0; kh < 3; ++kh)
#pragma unroll
        for (int kw = 0; kw < 3; ++kw) {
            int off = (y + kh) * WW + xc + kw;
            ss += P2[off];
            sx += P2[HH * WW + off];
        }
    rnB[i] = 1.f / (sqrtf(ss) + 1e-8f);
    n2B[i] = ss;
    win2x[i] = sx;
}

// ---- 3: pack patches to bf16 [LPAD][DD]; A = raw x, B = normalized style ----
__global__ __launch_bounds__(256) void k_pack(const float* __restrict__ x,
                                              const float* __restrict__ st,
                                              const float* __restrict__ rnB,
                                              ushort_t* __restrict__ A,
                                              ushort_t* __restrict__ Bm) {
    int row = blockIdx.x;
    bool isB = row >= LPAD;
    int i = isB ? row - LPAD : row;
    ushort_t* dst = (isB ? Bm : A) + (size_t)i * DD + threadIdx.x * 9;
    if (i >= LL) {
#pragma unroll
        for (int k = 0; k < 9; ++k) dst[k] = 0;
        return;
    }
    int y = i / HO, xc = i % HO;
    const float* src = isB ? st : x;
    float scale = isB ? rnB[i] : 1.f;
    const float* base = src + (size_t)threadIdx.x * (HH * WW) + y * WW + xc;
#pragma unroll
    for (int kh = 0; kh < 3; ++kh)
#pragma unroll
        for (int kw = 0; kw < 3; ++kw)
            dst[kh * 3 + kw] = f2bf(base[kh * WW + kw] * scale);
}

// ---- 4: fused GEMM (A * B^T) + per-row argmax, quadrant sub-phase schedule ----
__global__ __launch_bounds__(512, 2) void k_gemm2(const ushort_t* __restrict__ A,
                                                  const ushort_t* __restrict__ Bm,
                                                  u64* __restrict__ best) {
    extern __shared__ __align__(16) ushort_t lds[];  // 128 KiB

    const int t = threadIdx.x;
    const int wid = t >> 6, lane = t & 63;
    const int wr = wid >> 2, wc = wid & 3;
    const int l15 = lane & 15, l4 = lane >> 4;

    // T1: bijective XCD swizzle (m204), nwg = 1225
    const int nwg = NT2 * NT2;
    const int q = nwg >> 3, r = nwg & 7;  // 153, 1
    const int bid = blockIdx.x;
    const int xcd = bid & 7, loc = bid >> 3;
    const int swz = ((xcd < r) ? xcd * (q + 1) : r * (q + 1) + (xcd - r) * q) + loc;
    const int it = swz / NT2, jt = swz % NT2;

    // staging source: thread t covers chunk c=t (rows 0..127 of panel) and
    // c=t+512 (rows 128..255); logical k-group pre-swizzled: (c&3)^((c>>3)&3)
    const int gsrc = (t & 3) ^ ((t >> 3) & 3);
    const ushort_t* pA0 = A  + (size_t)(it * BM2 + (t >> 2)) * DD + gsrc * 8;
    const ushort_t* pB0 = Bm + (size_t)(jt * BM2 + (t >> 2)) * DD + gsrc * 8;

    // fragment read offsets (swizzled): phys group = l4 ^ ((row>>1)&3)
    const int sp8 = (l4 ^ ((l15 >> 1) & 3)) * 8;
    int aoff[8], boff[4];
#pragma unroll
    for (int mi = 0; mi < 8; ++mi)
        aoff[mi] = (wr * 128 + mi * 16 + l15) * 32 + sp8;
#pragma unroll
    for (int ni = 0; ni < 4; ++ni)
        boff[ni] = (wc * 64 + ni * 16 + l15) * 32 + sp8;

    f32x4 acc[8][4];
#pragma unroll
    for (int mi = 0; mi < 8; ++mi)
#pragma unroll
        for (int ni = 0; ni < 4; ++ni)
            acc[mi][ni] = (f32x4){0.f, 0.f, 0.f, 0.f};

    // prologue: stage slices 0,1,2 (A then B per slice, slice-ordered queue)
#define PSTAGE(S)                                                            \
    do {                                                                     \
        const ushort_t* sa = pA0 + (size_t)(S) * 32;                         \
        const ushort_t* sb = pB0 + (size_t)(S) * 32;                         \
        gload16(sa,          lds + (S) * ASL + t * 8);                       \
        gload16(sa + 294912, lds + (S) * ASL + 4096 + t * 8);                \
        gload16(sb,          lds + BBASE + (S) * ASL + t * 8);               \
        gload16(sb + 294912, lds + BBASE + (S) * ASL + 4096 + t * 8);        \
    } while (0)
    PSTAGE(0); PSTAGE(1); PSTAGE(2);
#undef PSTAGE
    asm volatile("s_waitcnt vmcnt(8)" ::: "memory");  // slice 0 landed
    __builtin_amdgcn_sched_barrier(0);
    __builtin_amdgcn_s_barrier();

    short8 af03[4], af47[4], bfr[4];

// SUB-A: 8 ds_reads (bfr + af03) | stage A-half of slice kb+U+3 | 16 MFMA m0-3
#define SUBA(U)                                                              \
    {                                                                        \
        _Pragma("unroll")                                                    \
        for (int ni = 0; ni < 4; ++ni)                                       \
            bfr[ni] = *(const short8*)(lds + BBASE + (U) * ASL + boff[ni]);  \
        _Pragma("unroll")                                                    \
        for (int mi = 0; mi < 4; ++mi)                                       \
            af03[mi] = *(const short8*)(lds + (U) * ASL + aoff[mi]);         \
        {                                                                    \
            const ushort_t* sa = pA0 + (size_t)(kb + (U) + 3) * 32;          \
            ushort_t* da = lds + (((U) + 3) & 3) * ASL + t * 8;              \
            gload16(sa,          da);                                        \
            gload16(sa + 294912, da + 4096);                                 \
        }                                                                    \
        __builtin_amdgcn_s_barrier();                                        \
        asm volatile("s_waitcnt lgkmcnt(0)" ::: "memory");                   \
        __builtin_amdgcn_sched_barrier(0);                                   \
        __builtin_amdgcn_s_setprio(1);                                       \
        _Pragma("unroll")                                                    \
        for (int mi = 0; mi < 4; ++mi)                                       \
            _Pragma("unroll")                                                \
            for (int ni = 0; ni < 4; ++ni)                                   \
                acc[mi][ni] = __builtin_amdgcn_mfma_f32_16x16x32_bf16(       \
                    af03[mi], bfr[ni], acc[mi][ni], 0, 0, 0);                \
        __builtin_amdgcn_s_setprio(0);                                       \
        __builtin_amdgcn_s_barrier();                                        \
    }

// SUB-B: 4 ds_reads (af47) | stage B-half | vmcnt(8) | 16 MFMA m4-7 (bfr reuse)
#define SUBB(U)                                                              \
    {                                                                        \
        _Pragma("unroll")                                                    \
        for (int mi = 0; mi < 4; ++mi)                                       \
            af47[mi] = *(const short8*)(lds + (U) * ASL + aoff[4 + mi]);     \
        {                                                                    \
            const ushort_t* sb = pB0 + (size_t)(kb + (U) + 3) * 32;          \
            ushort_t* db = lds + BBASE + (((U) + 3) & 3) * ASL + t * 8;      \
            gload16(sb,          db);                                        \
            gload16(sb + 294912, db + 4096);                                 \
        }                                                                    \
        asm volatile("s_waitcnt vmcnt(8)" ::: "memory");                     \
        __builtin_amdgcn_sched_barrier(0);                                   \
        __builtin_amdgcn_s_barrier();                                        \
        asm volatile("s_waitcnt lgkmcnt(0)" ::: "memory");                   \
        __builtin_amdgcn_sched_barrier(0);                                   \
        __builtin_amdgcn_s_setprio(1);                                       \
        _Pragma("unroll")                                                    \
        for (int mi = 0; mi < 4; ++mi)                                       \
            _Pragma("unroll")                                                \
            for (int ni = 0; ni < 4; ++ni)                                   \
                acc[4 + mi][ni] = __builtin_amdgcn_mfma_f32_16x16x32_bf16(   \
                    af47[mi], bfr[ni], acc[4 + mi][ni], 0, 0, 0);            \
        __builtin_amdgcn_s_setprio(0);                                       \
        __builtin_amdgcn_s_barrier();                                        \
    }

    for (int kt = 0; kt < NPH / 4; ++kt) {
        const int kb = kt * 4;
        SUBA(0) SUBB(0)
        SUBA(1) SUBB(1)
        SUBA(2) SUBB(2)
        SUBA(3) SUBB(3)
    }
#undef SUBA
#undef SUBB

    // epilogue: per output row, max over this block's 256 j's, merge globally
    const int jbase = jt * BM2 + wc * 64 + l15;
#pragma unroll
    for (int mi = 0; mi < 8; ++mi) {
#pragma unroll
        for (int rr = 0; rr < 4; ++rr) {
            float bv = -3.4e38f;
            int bj = 0x7FFFFFFF;
#pragma unroll
            for (int ni = 0; ni < 4; ++ni) {
                int j = jbase + ni * 16;
                float v = acc[mi][ni][rr];
                if (j < LL && (v > bv || (v == bv && j < bj))) { bv = v; bj = j; }
            }
#pragma unroll
            for (int m = 1; m < 16; m <<= 1) {
                float ov = __shfl_xor(bv, m, 64);
                int oj = __shfl_xor(bj, m, 64);
                if (ov > bv || (ov == bv && oj < bj)) { bv = ov; bj = oj; }
            }
            if (l15 == 0) {
                int i = it * BM2 + wr * 128 + mi * 16 + l4 * 4 + rr;
                if (i < LL) {
                    unsigned u = __float_as_uint(bv);
                    unsigned s = (bv < 0.f) ? ~u : (u | 0x80000000u);
                    u64 packed = ((u64)s << 32) | (unsigned)(~(unsigned)bj);
                    atomicMax(&best[i], packed);
                }
            }
        }
    }
}

// ---- 5: final scalar ----
__global__ __launch_bounds__(256) void k_final(const u64* __restrict__ best,
                                               const float* __restrict__ rnB,
                                               const float* __restrict__ n2B,
                                               const float* __restrict__ win2x,
                                               float* __restrict__ out) {
    int i = blockIdx.x * 256 + threadIdx.x;
    float contrib = 0.f;
    if (i < LL) {
        u64 p = best[i];
        unsigned s = (unsigned)(p >> 32);
        unsigned ub = (s & 0x80000000u) ? (s & 0x7FFFFFFFu) : ~s;
        float bv = __uint_as_float(ub);
        int j = (int)(~(unsigned)(p & 0xFFFFFFFFull));
        float dot = bv / rnB[j];
        contrib = win2x[i] + n2B[j] - 2.f * dot;
    }
    float sred = contrib;
#pragma unroll
    for (int o = 32; o > 0; o >>= 1) sred += __shfl_down(sred, o, 64);
    __shared__ float red[4];
    if ((threadIdx.x & 63) == 0) red[threadIdx.x >> 6] = sred;
    __syncthreads();
    if (threadIdx.x == 0) {
        float tot = red[0] + red[1] + red[2] + red[3];
        atomicAdd(out, tot * (1.0f / ((float)DD * (float)LL)));
    }
}

extern "C" void kernel_launch(void* const* d_in, const int* in_sizes, int n_in,
                              void* d_out, int out_size, void* d_ws, size_t ws_size,
                              hipStream_t stream) {
    const float* x  = (const float*)d_in[0];
    const float* st = (const float*)d_in[1];
    char* ws = (char*)d_ws;

    ushort_t* A    = (ushort_t*)ws;
    ushort_t* Bm   = (ushort_t*)(ws + OFF_B);
    float* rnB     = (float*)(ws + OFF_RNB);
    float* n2B     = (float*)(ws + OFF_N2B);
    float* win2x   = (float*)(ws + OFF_W2X);
    float* P2      = (float*)(ws + OFF_P2);
    u64* best      = (u64*)(ws + OFF_BEST);
    float* out     = (float*)d_out;

    hipFuncSetAttribute((const void*)k_gemm2,
                        hipFuncAttributeMaxDynamicSharedMemorySize, 131072);

    hipMemsetAsync(best, 0, (size_t)LL * 8, stream);
    hipMemsetAsync(out, 0, sizeof(float), stream);

    k_chan_sumsq<<<dim3(72), dim3(256), 0, stream>>>(st, x, P2);
    k_win<<<dim3(35), dim3(256), 0, stream>>>(P2, rnB, n2B, win2x);
    k_pack<<<dim3(2 * LPAD), dim3(256), 0, stream>>>(x, st, rnB, A, Bm);
    k_gemm2<<<dim3(NT2 * NT2), dim3(512), 131072, stream>>>(A, Bm, best);
    k_final<<<dim3(35), dim3(256), 0, stream>>>(best, rnB, n2B, win2x, out);
}